// Round 2
// 1476.918 us; speedup vs baseline: 2.9951x; 2.9951x over previous
//
#include <hip/hip_runtime.h>

// Problem constants (fixed by reference)
#define BB 4
#define HH 16
#define SS 2048
#define DD 64
#define BHT 64            // BB*HH

#define SCALE 0.125f
#define MASK_FILL -1e10f

// main kernel tiling
#define BM 128            // q rows per block (4 waves x 32 rows)
#define BN 64             // kv cols per tile
#define NJT (SS / BN)     // 32
#define NT 256

// packed bytes per (bh, j-block): K bf16 hi/lo 16KB + V f16 hi/lo 16KB
// K frag (A of T=K*Q):    j = tile*16+(l&15), d = ks*32+(l>>4)*8+e
// V frag (A of O^T=V^T*P^T): d = tile*16+(l&15), j = ks*32+(l>>4)*8+e
#define KVBLK 32768

typedef __attribute__((ext_vector_type(4))) float f32x4;
typedef __attribute__((ext_vector_type(4))) int   i32x4;
typedef __attribute__((ext_vector_type(2))) unsigned int u32x2;
typedef __attribute__((ext_vector_type(8))) short bfrag;      // 8x bf16 bits
typedef __attribute__((ext_vector_type(8))) _Float16 hfrag;   // 8x f16

#define MFMA_BF16(A, B, C) __builtin_amdgcn_mfma_f32_16x16x32_bf16((A), (B), (C), 0, 0, 0)
#define MFMA_F16(A, B, C)  __builtin_amdgcn_mfma_f32_16x16x32_f16((A), (B), (C), 0, 0, 0)

__device__ __forceinline__ unsigned short f2bf(float x) {
  unsigned u = __float_as_uint(x);
  return (unsigned short)((u + 0x7FFFu + ((u >> 16) & 1u)) >> 16);
}
__device__ __forceinline__ float bf2f(unsigned short h) {
  return __uint_as_float(((unsigned)h) << 16);
}
__device__ __forceinline__ unsigned short f2h(float x) {
  union { _Float16 h; unsigned short u; } cv;
  cv.h = (_Float16)x;
  return cv.u;
}
__device__ __forceinline__ float h2f(unsigned short b) {
  union { _Float16 h; unsigned short u; } cv;
  cv.u = b;
  return (float)cv.h;
}

// ---------------- pre-pack: K -> bf16 hi/lo, V -> f16 hi/lo, frag-linear ----
__global__ __launch_bounds__(256) void sdpa_pack(
    const float* __restrict__ k, const float* __restrict__ v,
    unsigned short* __restrict__ kvp)
{
  __shared__ float Kf[64][68];   // [d][j] (+pad)
  __shared__ float Vf[64][68];   // [j][d] (+pad)
  const int jb = blockIdx.x, bh = blockIdx.y, t = threadIdx.x;
  const int j0 = jb * BN;
  const int r0 = t >> 4, c4 = (t & 15) * 4;
  const float* kbase = k + (size_t)bh * DD * SS;   // k is [bh][d][s]
  const float* vbase = v + (size_t)bh * SS * DD;   // v is [bh][s][d]
#pragma unroll
  for (int p = 0; p < 4; ++p) {
    const int rr = r0 + p * 16;
    *(f32x4*)&Kf[rr][c4] = *(const f32x4*)&kbase[(size_t)rr * SS + j0 + c4];
    *(f32x4*)&Vf[rr][c4] = *(const f32x4*)&vbase[(size_t)(j0 + rr) * DD + c4];
  }
  __syncthreads();
  unsigned short* blk = kvp + ((size_t)bh * NJT + jb) * (KVBLK / 2);
#pragma unroll
  for (int p = 0; p < 2; ++p) {
    const int s = t + p * 256;
    const int lane = s & 63, ks = (s >> 6) & 1, tile = (s >> 7) & 3;
    const int lif = lane & 15, gf = lane >> 4;
    bfrag khi, klo, vhi, vlo;
#pragma unroll
    for (int e = 0; e < 8; ++e) {
      float x = Kf[ks * 32 + gf * 8 + e][tile * 16 + lif];
      unsigned short hb = f2bf(x);
      khi[e] = (short)hb;
      klo[e] = (short)f2bf(x - bf2f(hb));
      float y = Vf[ks * 32 + gf * 8 + e][tile * 16 + lif];
      unsigned short hh = f2h(y);
      vhi[e] = (short)hh;
      vlo[e] = (short)f2h(y - h2f(hh));
    }
    const size_t so = (size_t)((tile * 2 + ks) * 2 * 64 + lane) * 8;  // ushort units
    *(bfrag*)(blk + so) = khi;
    *(bfrag*)(blk + so + 512) = klo;          // +1024 B (lo plane)
    *(bfrag*)(blk + 8192 + so) = vhi;         // V region @ +16384 B
    *(bfrag*)(blk + 8192 + so + 512) = vlo;
  }
}

// ---------------- fused attention: QK bf16x3 MFMA, PV f16-hi/lo MFMA --------
// PACKED=1: fragments pre-packed in workspace. PACKED=0: raw f32 K/V staged to
// LDS, fragments converted on the fly (no workspace needed).
template<int PACKED>
__global__ __launch_bounds__(NT, 2) void sdpa_mfma(
    const float* __restrict__ q, const float* __restrict__ kg,
    const float* __restrict__ vg, const int* __restrict__ mask,
    const unsigned short* __restrict__ kv,
    float* __restrict__ out, float* __restrict__ score)
{
  __shared__ __align__(16) char kvbuf[2][KVBLK];   // 64 KB (packed frags OR raw f32 K|V)
  __shared__ __align__(16) char pbuf[4][4096];     // per-wave P frag staging (16 KB)

  const int tid = threadIdx.x;
  const int w = tid >> 6, l = tid & 63;
  const int li = l & 15, g = l >> 4;
  const int bh = blockIdx.y, b = bh >> 4;          // H == 16
  const int i0 = blockIdx.x * BM;

  const int r0s = tid >> 4, c4s = (tid & 15) * 4;  // fallback staging decomposition

  const float* kbase = kg + (size_t)bh * DD * SS;
  const float* vbase = vg + (size_t)bh * SS * DD;
  const int* mbase = mask + (size_t)b * SS * SS;
  const char* kvsrc = nullptr;
  if constexpr (PACKED) kvsrc = (const char*)kv + (size_t)bh * NJT * KVBLK;

  // ---- Q fragments (B of T=K*Q): i = li, d = ks*32 + g*8 + e ----
  bfrag Qh[2][2], Ql[2][2];
#pragma unroll
  for (int it = 0; it < 2; ++it) {
    const int ig = i0 + w * 32 + it * 16 + li;
#pragma unroll
    for (int ks = 0; ks < 2; ++ks) {
      const float* qp = q + ((size_t)bh * SS + ig) * DD + ks * 32 + g * 8;
      f32x4 a = *(const f32x4*)qp;
      f32x4 c = *(const f32x4*)(qp + 4);
      float xs[8] = {a.x, a.y, a.z, a.w, c.x, c.y, c.z, c.w};
#pragma unroll
      for (int e = 0; e < 8; ++e) {
        unsigned short hb = f2bf(xs[e]);
        Qh[it][ks][e] = (short)hb;
        Ql[it][ks][e] = (short)f2bf(xs[e] - bf2f(hb));
      }
    }
  }

  auto stage_load = [&](f32x4* pf, int jt_) {
    if constexpr (PACKED) {
      const char* src = kvsrc + (size_t)jt_ * KVBLK;
#pragma unroll
      for (int r = 0; r < 8; ++r)
        pf[r] = *(const f32x4*)(src + tid * 16 + r * 4096);
    } else {
      const int j0_ = jt_ * BN;
#pragma unroll
      for (int p = 0; p < 4; ++p) {
        const int rr = r0s + p * 16;
        pf[p]     = *(const f32x4*)&kbase[(size_t)rr * SS + j0_ + c4s];
        pf[4 + p] = *(const f32x4*)&vbase[(size_t)(j0_ + rr) * DD + c4s];
      }
    }
  };
  auto stage_write = [&](const f32x4* pf, int bufi) {
    char* dst = kvbuf[bufi];
    if constexpr (PACKED) {
#pragma unroll
      for (int r = 0; r < 8; ++r)
        *(f32x4*)(dst + tid * 16 + r * 4096) = pf[r];
    } else {
#pragma unroll
      for (int p = 0; p < 4; ++p) {
        const int rr = r0s + p * 16;
        *(f32x4*)(dst + (rr * 64 + c4s) * 4) = pf[p];               // Kf f32 [d][j]
        *(f32x4*)(dst + 16384 + (rr * 64 + c4s) * 4) = pf[4 + p];   // Vf f32 [j][d]
      }
    }
  };

  float m_i[2] = {-3.0e38f, -3.0e38f};
  float l_i[2] = {0.0f, 0.0f};
  f32x4 Oacc[2][4] = {};   // O^T tiles: row d = dt*16+g*4+r, col i = li

  // prologue: stage tile 0
  {
    f32x4 t0[8];
    stage_load(t0, 0);
    stage_write(t0, 0);
  }
  __syncthreads();

  for (int jt = 0; jt < NJT; ++jt) {
    const int j0 = jt * BN;
    const char* kb = kvbuf[jt & 1];

    // prefetch next KV tile into registers (written to other LDS buf at end)
    f32x4 pf[8];
    if (jt + 1 < NJT) stage_load(pf, jt + 1);

    // mask loads (long latency — issue early)
    i32x4 mk[2][4];
#pragma unroll
    for (int it = 0; it < 2; ++it) {
      const int ig = i0 + w * 32 + it * 16 + li;
#pragma unroll
      for (int jtile = 0; jtile < 4; ++jtile)
        mk[it][jtile] = *(const i32x4*)(mbase + (size_t)ig * SS + j0 + jtile * 16 + g * 4);
    }

    // ---- T = K*Q = S^T, bf16x3.  C: row j = jtile*16+g*4+r, col i = li ----
    f32x4 Tacc[2][4];
#pragma unroll
    for (int jtile = 0; jtile < 4; ++jtile) {
      bfrag Kh0, Kl0, Kh1, Kl1;
      if constexpr (PACKED) {
        Kh0 = *(const bfrag*)(kb + (jtile * 4 + 0) * 1024 + l * 16);
        Kl0 = *(const bfrag*)(kb + (jtile * 4 + 1) * 1024 + l * 16);
        Kh1 = *(const bfrag*)(kb + (jtile * 4 + 2) * 1024 + l * 16);
        Kl1 = *(const bfrag*)(kb + (jtile * 4 + 3) * 1024 + l * 16);
      } else {
        const float* Kf = (const float*)kb;
#pragma unroll
        for (int e = 0; e < 8; ++e) {
          float x0 = Kf[(g * 8 + e) * 64 + jtile * 16 + li];
          unsigned short h0 = f2bf(x0);
          Kh0[e] = (short)h0; Kl0[e] = (short)f2bf(x0 - bf2f(h0));
          float x1 = Kf[(32 + g * 8 + e) * 64 + jtile * 16 + li];
          unsigned short h1 = f2bf(x1);
          Kh1[e] = (short)h1; Kl1[e] = (short)f2bf(x1 - bf2f(h1));
        }
      }
#pragma unroll
      for (int it = 0; it < 2; ++it) {
        f32x4 t = {0.f, 0.f, 0.f, 0.f};
        t = MFMA_BF16(Kl0, Qh[it][0], t);
        t = MFMA_BF16(Kh0, Ql[it][0], t);
        t = MFMA_BF16(Kh0, Qh[it][0], t);
        t = MFMA_BF16(Kl1, Qh[it][1], t);
        t = MFMA_BF16(Kh1, Ql[it][1], t);
        t = MFMA_BF16(Kh1, Qh[it][1], t);
        Tacc[it][jtile] = t;
      }
    }

    // ---- mask+scale, score write (nt), online softmax, P(f16 hi/lo) ----
    u32x2 lohold[2][4];
#pragma unroll
    for (int it = 0; it < 2; ++it) {
      const int ig = i0 + w * 32 + it * 16 + li;
      float* sb = score + ((size_t)bh * SS + ig) * SS + j0 + g * 4;
      float pm = -3.0e38f;
#pragma unroll
      for (int jtile = 0; jtile < 4; ++jtile) {
        f32x4 t = Tacc[it][jtile];
        i32x4 m4 = mk[it][jtile];
        t.x = m4.x ? t.x * SCALE : MASK_FILL;
        t.y = m4.y ? t.y * SCALE : MASK_FILL;
        t.z = m4.z ? t.z * SCALE : MASK_FILL;
        t.w = m4.w ? t.w * SCALE : MASK_FILL;
        __builtin_nontemporal_store(t, (f32x4*)(sb + jtile * 16));
        pm = fmaxf(pm, fmaxf(fmaxf(t.x, t.y), fmaxf(t.z, t.w)));
        Tacc[it][jtile] = t;
      }
      pm = fmaxf(pm, __shfl_xor(pm, 16));
      pm = fmaxf(pm, __shfl_xor(pm, 32));
      const float mnew = fmaxf(m_i[it], pm);
      const float alpha = __expf(m_i[it] - mnew);
      m_i[it] = mnew;
      float ps = 0.0f;
#pragma unroll
      for (int jtile = 0; jtile < 4; ++jtile) {
        f32x4 t = Tacc[it][jtile];
        float p0 = __expf(t.x - mnew), p1 = __expf(t.y - mnew);
        float p2 = __expf(t.z - mnew), p3 = __expf(t.w - mnew);
        ps += (p0 + p1) + (p2 + p3);
        unsigned short h0 = f2h(p0), h1 = f2h(p1), h2v = f2h(p2), h3 = f2h(p3);
        u32x2 hi_, lo_;
        hi_.x = (unsigned)h0 | ((unsigned)h1 << 16);
        hi_.y = (unsigned)h2v | ((unsigned)h3 << 16);
        lo_.x = (unsigned)f2h(p0 - h2f(h0)) | ((unsigned)f2h(p1 - h2f(h1)) << 16);
        lo_.y = (unsigned)f2h(p2 - h2f(h2v)) | ((unsigned)f2h(p3 - h2f(h3)) << 16);
        // B-frag slot: lane dl = li + 16*((j>>3)&3), byte (j&7)*2, plane it*2 + (j>>5)
        const int jA = jtile * 16 + g * 4;
        const int dl = li + 16 * ((jA >> 3) & 3);
        *(u32x2*)(pbuf[w] + (it * 2 + (jA >> 5)) * 1024 + dl * 16 + (jA & 7) * 2) = hi_;
        lohold[it][jtile] = lo_;
      }
      ps += __shfl_xor(ps, 16);
      ps += __shfl_xor(ps, 32);
      l_i[it] = l_i[it] * alpha + ps;
#pragma unroll
      for (int dt = 0; dt < 4; ++dt) Oacc[it][dt] *= alpha;
    }

    // two-pass P staging through wave-private pbuf: read hi, overwrite with lo
    hfrag Pfh[2][2], Pfl[2][2];
#pragma unroll
    for (int it = 0; it < 2; ++it)
#pragma unroll
      for (int ks = 0; ks < 2; ++ks)
        Pfh[it][ks] = *(const hfrag*)(pbuf[w] + (it * 2 + ks) * 1024 + l * 16);
#pragma unroll
    for (int it = 0; it < 2; ++it)
#pragma unroll
      for (int jtile = 0; jtile < 4; ++jtile) {
        const int jA = jtile * 16 + g * 4;
        const int dl = li + 16 * ((jA >> 3) & 3);
        *(u32x2*)(pbuf[w] + (it * 2 + (jA >> 5)) * 1024 + dl * 16 + (jA & 7) * 2) = lohold[it][jtile];
      }
#pragma unroll
    for (int it = 0; it < 2; ++it)
#pragma unroll
      for (int ks = 0; ks < 2; ++ks)
        Pfl[it][ks] = *(const hfrag*)(pbuf[w] + (it * 2 + ks) * 1024 + l * 16);

    // ---- O^T += V^T * P^T  (f16: Vh*Ph + Vh*Pl + Vl*Ph) ----
#pragma unroll
    for (int dt = 0; dt < 4; ++dt) {
      hfrag Vh0, Vl0, Vh1, Vl1;
      if constexpr (PACKED) {
        Vh0 = *(const hfrag*)(kb + 16384 + (dt * 4 + 0) * 1024 + l * 16);
        Vl0 = *(const hfrag*)(kb + 16384 + (dt * 4 + 1) * 1024 + l * 16);
        Vh1 = *(const hfrag*)(kb + 16384 + (dt * 4 + 2) * 1024 + l * 16);
        Vl1 = *(const hfrag*)(kb + 16384 + (dt * 4 + 3) * 1024 + l * 16);
      } else {
        const float* Vf = (const float*)(kb + 16384);
#pragma unroll
        for (int e = 0; e < 8; ++e) {
          float y0 = Vf[(g * 8 + e) * 64 + dt * 16 + li];
          unsigned short h0 = f2h(y0);
          Vh0[e] = __builtin_bit_cast(_Float16, h0);
          Vl0[e] = (_Float16)(y0 - h2f(h0));
          float y1 = Vf[(32 + g * 8 + e) * 64 + dt * 16 + li];
          unsigned short h1 = f2h(y1);
          Vh1[e] = __builtin_bit_cast(_Float16, h1);
          Vl1[e] = (_Float16)(y1 - h2f(h1));
        }
      }
#pragma unroll
      for (int it = 0; it < 2; ++it) {
        f32x4 o = Oacc[it][dt];
        o = MFMA_F16(Vl0, Pfh[it][0], o);
        o = MFMA_F16(Vh0, Pfl[it][0], o);
        o = MFMA_F16(Vh0, Pfh[it][0], o);
        o = MFMA_F16(Vl1, Pfh[it][1], o);
        o = MFMA_F16(Vh1, Pfl[it][1], o);
        o = MFMA_F16(Vh1, Pfh[it][1], o);
        Oacc[it][dt] = o;
      }
    }

    // write prefetched tile into the other buffer, then one barrier per iter
    if (jt + 1 < NJT) stage_write(pf, (jt + 1) & 1);
    __syncthreads();
  }

  // ---- epilogue: O = O^T / l ----
#pragma unroll
  for (int it = 0; it < 2; ++it) {
    const int ig = i0 + w * 32 + it * 16 + li;
    const float inv = 1.0f / l_i[it];
    float* ob = out + ((size_t)bh * SS + ig) * DD + g * 4;
#pragma unroll
    for (int dt = 0; dt < 4; ++dt) {
      f32x4 o = Oacc[it][dt] * inv;
      __builtin_nontemporal_store(o, (f32x4*)(ob + dt * 16));
    }
  }
}

extern "C" void kernel_launch(void* const* d_in, const int* in_sizes, int n_in,
                              void* d_out, int out_size, void* d_ws, size_t ws_size,
                              hipStream_t stream) {
  const float* q    = (const float*)d_in[0];
  const float* k    = (const float*)d_in[1];
  const float* v    = (const float*)d_in[2];
  const int*   mask = (const int*)d_in[3];
  float* out   = (float*)d_out;
  float* score = out + (size_t)BB * HH * SS * DD;   // outputs concatenated: (output, attn_score)

  const size_t need = (size_t)BHT * NJT * KVBLK;    // 64 MiB
  if (d_ws != nullptr && ws_size >= need) {
    unsigned short* kvp = (unsigned short*)d_ws;
    hipLaunchKernelGGL(sdpa_pack, dim3(NJT, BHT), dim3(256), 0, stream, k, v, kvp);
    hipLaunchKernelGGL((sdpa_mfma<1>), dim3(SS / BM, BHT), dim3(NT), 0, stream,
                       q, k, v, mask, kvp, out, score);
  } else {
    hipLaunchKernelGGL((sdpa_mfma<0>), dim3(SS / BM, BHT), dim3(NT), 0, stream,
                       q, k, v, mask, (const unsigned short*)nullptr, out, score);
  }
}